// Round 10
// baseline (216.837 us; speedup 1.0000x reference)
//
#include <hip/hip_runtime.h>
#include <hip/hip_bf16.h>
#include <hip/hip_cooperative_groups.h>

// Problem constants
#define NSEG   4480     // 70 * 64
#define ADIM   64
#define BDIM   16
#define NEDGE  65536
#define UPITCH 1088     // bf16 elements per U row: 1024 kernel-cols + 64 bias-cols (2176 B)
#define KP     72       // LDS pitch (bf16 elems): 64 + 8 pad
#define NTILE  1190     // 70 x 17 proj tiles
#define GRID   1024     // cooperative grid: 4 blocks/CU (LDS 18.4KB x4, VGPR<=128)

typedef __bf16 bf16x8 __attribute__((ext_vector_type(8)));
typedef float  f32x4  __attribute__((ext_vector_type(4)));

__device__ __forceinline__ float bf2f(unsigned int bits_hi16) {
    union { unsigned int i; float f; } c; c.i = bits_hi16; return c.f;
}
__device__ __forceinline__ unsigned short f2bf(float f) {
    union { float f; unsigned int i; } c; c.f = f;
    unsigned int x = c.i;
    x += 0x7fffu + ((x >> 16) & 1u);   // round-to-nearest-even
    return (unsigned short)(x >> 16);
}

// ---------------------------------------------------------------------------
// fused_kernel: phase 1 = MFMA projection U = atom x W (bf16 out, r8 body,
// grid-strided over the 1190 tiles; tiles<70 also zero out[]); grid.sync();
// phase 2 = r8's one-wave-per-edge message+scatter, grid-strided (16
// independent edge iterations per wave -> extra MLP).
// Cooperative launch: 1024 blocks co-resident (4/CU), one dispatch node
// instead of two — removes one CP round-trip (~1-2 us of the 92.4 total).
// ---------------------------------------------------------------------------
__global__ __launch_bounds__(256, 4) void fused_kernel(
    const float* __restrict__ atom,
    const float* __restrict__ bond,
    const int*   __restrict__ pair,
    const float* __restrict__ kern,
    const float* __restrict__ bias,
    unsigned short* __restrict__ U,
    float* __restrict__ out)
{
    __shared__ unsigned short Al[64 * KP];   // A_bf16[row][k]
    __shared__ unsigned short Wl[64 * KP];   // W_bf16[c][k]

    const int t    = threadIdx.x;
    const int lane = t & 63;
    const int w    = t >> 6;

    // ================= phase 1: projection =================
    for (int tile = blockIdx.x; tile < NTILE; tile += GRID) {
        const int bx = tile % 70;           // atom-row tile
        const int by = tile / 70;           // col tile (16 = bias)
        const int a_base = bx * 64;
        const int c_base = by * 64;

        if (by == 0) {
            // zero out[]: 4480*64 f32 = 17920 float4; tiles 0..69 x 256 thr exact
            int gid = bx * 256 + t;
            ((float4*)out)[gid] = make_float4(0.f, 0.f, 0.f, 0.f);
        }

        // ---- stage A tile: thread t -> row t>>2, k-quarter (t&3)*16 ----
        {
            const int row = t >> 2, q = t & 3;
            const float4* src = (const float4*)(atom + (size_t)(a_base + row) * ADIM + q * 16);
            unsigned short* dst = Al + row * KP + q * 16;
#pragma unroll
            for (int i = 0; i < 4; ++i) {
                float4 v = src[i];
                dst[i * 4 + 0] = f2bf(v.x);
                dst[i * 4 + 1] = f2bf(v.y);
                dst[i * 4 + 2] = f2bf(v.z);
                dst[i * 4 + 3] = f2bf(v.w);
            }
        }
        // ---- stage W tile (k-dim contiguous in kern/bias) ----
        {
            const int crow = t >> 2, q = t & 3;
            const int c = c_base + crow;
            const float* bsrc = (c < 1024)
                ? (kern + (size_t)(c & 15) * 4096 + (size_t)(c >> 4) * 64)
                : (bias + (size_t)(c - 1024) * 64);
            const float4* src = (const float4*)(bsrc + q * 16);
            unsigned short* dst = Wl + crow * KP + q * 16;
#pragma unroll
            for (int i = 0; i < 4; ++i) {
                float4 v = src[i];
                dst[i * 4 + 0] = f2bf(v.x);
                dst[i * 4 + 1] = f2bf(v.y);
                dst[i * 4 + 2] = f2bf(v.z);
                dst[i * 4 + 3] = f2bf(v.w);
            }
        }
        __syncthreads();

        const int m    = lane & 15;
        const int quad = lane >> 4;

        f32x4 acc[4] = {{0.f,0.f,0.f,0.f},{0.f,0.f,0.f,0.f},
                        {0.f,0.f,0.f,0.f},{0.f,0.f,0.f,0.f}};

#pragma unroll
        for (int kk = 0; kk < 2; ++kk) {
            bf16x8 a = *(const bf16x8*)(Al + (w * 16 + m) * KP + kk * 32 + quad * 8);
#pragma unroll
            for (int ct = 0; ct < 4; ++ct) {
                bf16x8 b = *(const bf16x8*)(Wl + (ct * 16 + m) * KP + kk * 32 + quad * 8);
                acc[ct] = __builtin_amdgcn_mfma_f32_16x16x32_bf16(a, b, acc[ct], 0, 0, 0);
            }
        }

#pragma unroll
        for (int ct = 0; ct < 4; ++ct) {
#pragma unroll
            for (int r = 0; r < 4; ++r) {
                U[(size_t)(a_base + w * 16 + quad * 4 + r) * UPITCH
                  + (c_base + ct * 16 + m)] = f2bf(acc[ct][r]);
            }
        }
        __syncthreads();   // LDS reuse across grid-stride iterations
    }

    // ================= grid-wide barrier =================
    cooperative_groups::this_grid().sync();

    // ================= phase 2: edge messages + scatter =================
    // 4096 waves x 16 iterations = 65536 edges (exact). Iterations are
    // independent -> the compiler can overlap loads across edges.
    const int wave_id = blockIdx.x * 4 + w;        // 0..4095
#pragma unroll 2
    for (int it = 0; it < NEDGE / (GRID * 4); ++it) {
        const int e = wave_id + (GRID * 4) * it;

        const int2 p  = ((const int2*)pair)[e];    // .x = dst, .y = src
        const unsigned short* urow = U + (size_t)p.y * UPITCH;
        const uint4* up = (const uint4*)(urow + lane * 16);
        uint4 w0 = up[0];
        uint4 w1 = up[1];

        const float4* bp = (const float4*)(bond + (size_t)e * BDIM);
        float4 b0 = bp[0], b1 = bp[1], b2 = bp[2], b3 = bp[3];
        float b[16] = { b0.x, b0.y, b0.z, b0.w,  b1.x, b1.y, b1.z, b1.w,
                        b2.x, b2.y, b2.z, b2.w,  b3.x, b3.y, b3.z, b3.w };

        unsigned int uw[8] = { w0.x, w0.y, w0.z, w0.w, w1.x, w1.y, w1.z, w1.w };

        float m = bf2f(((unsigned int)urow[1024 + lane]) << 16);   // bias col
#pragma unroll
        for (int q = 0; q < 8; ++q) {
            float lo = bf2f(uw[q] << 16);           // element b = 2q
            float hi = bf2f(uw[q] & 0xffff0000u);   // element b = 2q+1
            m = fmaf(lo, b[2 * q],     m);
            m = fmaf(hi, b[2 * q + 1], m);
        }

        atomicAdd(out + (size_t)p.x * ADIM + lane, m);
    }
}

extern "C" void kernel_launch(void* const* d_in, const int* in_sizes, int n_in,
                              void* d_out, int out_size, void* d_ws, size_t ws_size,
                              hipStream_t stream) {
    const float* atom = (const float*)d_in[0];   // [4480, 64]  f32
    const float* bond = (const float*)d_in[1];   // [65536, 16] f32
    const int*   pair = (const int*)  d_in[2];   // [65536, 2]  int32
    const float* kern = (const float*)d_in[3];   // [16, 4096]  f32
    const float* bias = (const float*)d_in[4];   // [4096]      f32

    float* out = (float*)d_out;                  // [4480, 64]  f32
    unsigned short* U = (unsigned short*)d_ws;   // [4480, 1088] bf16 = 9.75 MB

    void* args[] = { (void*)&atom, (void*)&bond, (void*)&pair, (void*)&kern,
                     (void*)&bias, (void*)&U, (void*)&out };
    hipLaunchCooperativeKernel((const void*)fused_kernel,
                               dim3(GRID), dim3(256), args, 0, stream);
}

// Round 11
// 92.336 us; speedup vs baseline: 2.3483x; 2.3483x over previous
//
#include <hip/hip_runtime.h>
#include <hip/hip_bf16.h>

// Problem constants
#define NSEG   4480     // 70 * 64
#define ADIM   64
#define BDIM   16
#define NEDGE  65536
#define UPITCH 1088     // bf16 elements per U row: 1024 kernel-cols + 64 bias-cols (2176 B)
#define KP     72       // LDS pitch (bf16 elems) for 64-deep K tiles: 64 + 8 pad (144 B rows)

typedef __bf16 bf16x8 __attribute__((ext_vector_type(8)));
typedef float  f32x4  __attribute__((ext_vector_type(4)));

__device__ __forceinline__ float bf2f(unsigned int bits_hi16) {
    union { unsigned int i; float f; } c; c.i = bits_hi16; return c.f;
}
__device__ __forceinline__ unsigned short f2bf(float f) {
    union { float f; unsigned int i; } c; c.f = f;
    unsigned int x = c.i;
    x += 0x7fffu + ((x >> 16) & 1u);   // round-to-nearest-even
    return (unsigned short)(x >> 16);
}

// ---------------------------------------------------------------------------
// proj_kernel (MFMA): U[a, c] = sum_j atom[a,j] * W[j,c], stored bf16.
//   W[j,c] = kern[c&15, (c>>4)*64 + j]  (c < 1024;  c = i*16+b)
//   W[j,1024+i] = bias[i*64+j]          (bias cols)
// Block = 64 rows x 64 cols, K = 64 whole. Stage A (atom) and W tiles as
// bf16 in LDS (W's k-dim is contiguous in kern -> coalesced staging), then
// 2x mfma_f32_16x16x32_bf16 per 16x16 tile. Per wave: 10 ds_read_b128 +
// 8 MFMA — 13x less LDS traffic than the VALU version (which was
// LDS-throughput-bound at ~12 us; this runs ~4 us).
// Fragment layouts (m89/m91-verified): A: m=lane&15, k=quad*8+j;
// B: n=lane&15, k=quad*8+j; C/D: col=lane&15, row=quad*4+reg.
// by==0 slice zeroes out[] (stream order covers edge_kernel's atomics).
// ---------------------------------------------------------------------------
__global__ __launch_bounds__(256) void proj_kernel(
    const float* __restrict__ atom,
    const float* __restrict__ kern,
    const float* __restrict__ bias,
    unsigned short* __restrict__ U,
    float* __restrict__ out)
{
    __shared__ unsigned short Al[64 * KP];   // A_bf16[row][k]
    __shared__ unsigned short Wl[64 * KP];   // W_bf16[c][k]  (n-major, k-contig)

    const int t      = threadIdx.x;
    const int bx     = blockIdx.x;      // 0..69  atom-row tile
    const int by     = blockIdx.y;      // 0..16  col tile (16 = bias)
    const int a_base = bx * 64;
    const int c_base = by * 64;

    if (by == 0) {
        // zero out[]: 4480*64 f32 = 17920 float4; 70 blocks * 256 threads exact
        int gid = bx * 256 + t;
        ((float4*)out)[gid] = make_float4(0.f, 0.f, 0.f, 0.f);
    }

    // ---- stage A tile: thread t -> row t>>2, k-quarter (t&3)*16 ----
    {
        const int row = t >> 2, q = t & 3;
        const float4* src = (const float4*)(atom + (size_t)(a_base + row) * ADIM + q * 16);
        unsigned short* dst = Al + row * KP + q * 16;
#pragma unroll
        for (int i = 0; i < 4; ++i) {
            float4 v = src[i];
            dst[i * 4 + 0] = f2bf(v.x);
            dst[i * 4 + 1] = f2bf(v.y);
            dst[i * 4 + 2] = f2bf(v.z);
            dst[i * 4 + 3] = f2bf(v.w);
        }
    }
    // ---- stage W tile: row c has its 64 k-values contiguous in kern/bias ----
    {
        const int crow = t >> 2, q = t & 3;
        const int c = c_base + crow;
        const float* bsrc = (c < 1024)
            ? (kern + (size_t)(c & 15) * 4096 + (size_t)(c >> 4) * 64)
            : (bias + (size_t)(c - 1024) * 64);
        const float4* src = (const float4*)(bsrc + q * 16);
        unsigned short* dst = Wl + crow * KP + q * 16;
#pragma unroll
        for (int i = 0; i < 4; ++i) {
            float4 v = src[i];
            dst[i * 4 + 0] = f2bf(v.x);
            dst[i * 4 + 1] = f2bf(v.y);
            dst[i * 4 + 2] = f2bf(v.z);
            dst[i * 4 + 3] = f2bf(v.w);
        }
    }
    __syncthreads();

    const int lane = t & 63;
    const int w    = t >> 6;        // wave id -> row sub-tile [w*16, w*16+16)
    const int m    = lane & 15;     // A row / B col / D col within tile
    const int quad = lane >> 4;

    f32x4 acc[4] = {{0.f,0.f,0.f,0.f},{0.f,0.f,0.f,0.f},
                    {0.f,0.f,0.f,0.f},{0.f,0.f,0.f,0.f}};

#pragma unroll
    for (int kk = 0; kk < 2; ++kk) {
        bf16x8 a = *(const bf16x8*)(Al + (w * 16 + m) * KP + kk * 32 + quad * 8);
#pragma unroll
        for (int ct = 0; ct < 4; ++ct) {
            bf16x8 b = *(const bf16x8*)(Wl + (ct * 16 + m) * KP + kk * 32 + quad * 8);
            acc[ct] = __builtin_amdgcn_mfma_f32_16x16x32_bf16(a, b, acc[ct], 0, 0, 0);
        }
    }

    // store: D row = w*16 + quad*4 + r, col = ct*16 + m (16 x 2B stores/lane;
    // each quad's 16 lanes cover a contiguous 32 B run -> L2-combinable)
#pragma unroll
    for (int ct = 0; ct < 4; ++ct) {
#pragma unroll
        for (int r = 0; r < 4; ++r) {
            U[(size_t)(a_base + w * 16 + quad * 4 + r) * UPITCH
              + (c_base + ct * 16 + m)] = f2bf(acc[ct][r]);
        }
    }
}

// ---------------------------------------------------------------------------
// edge_kernel: one wave per edge; lane i computes msg[e,i].
//   msg[e,i] = sum_b bond[e,b] * U[src, i*16+b]  +  U[src, 1024+i]
// Lane i reads its 16 bf16 weights as 2 contiguous uint4 (the wave streams
// the whole 2176 B row coalesced). 65536 independent waves — the gather runs
// at the ~7.6 TB/s L3 ceiling (143 MB -> ~18 us), which five structural
// alternatives (grouping x3, store+reduce, fusion) all failed to beat.
// ---------------------------------------------------------------------------
__global__ __launch_bounds__(256) void edge_kernel(
    const float*          __restrict__ bond,
    const int*            __restrict__ pair,
    const unsigned short* __restrict__ U,
    float*                __restrict__ out)
{
    const int t    = threadIdx.x;
    const int lane = t & 63;
    const int e    = blockIdx.x * 4 + (t >> 6);

    const int2 p  = ((const int2*)pair)[e];   // .x = dst, .y = src
    const int dst = p.x;
    const int src = p.y;

    const unsigned short* urow = U + (size_t)src * UPITCH;
    const uint4* up = (const uint4*)(urow + lane * 16);
    uint4 w0 = up[0];
    uint4 w1 = up[1];

    const float4* bp = (const float4*)(bond + (size_t)e * BDIM);
    float4 b0 = bp[0], b1 = bp[1], b2 = bp[2], b3 = bp[3];
    float b[16] = { b0.x, b0.y, b0.z, b0.w,  b1.x, b1.y, b1.z, b1.w,
                    b2.x, b2.y, b2.z, b2.w,  b3.x, b3.y, b3.z, b3.w };

    unsigned int w[8] = { w0.x, w0.y, w0.z, w0.w, w1.x, w1.y, w1.z, w1.w };

    float m = bf2f(((unsigned int)urow[1024 + lane]) << 16);   // bias col
#pragma unroll
    for (int q = 0; q < 8; ++q) {
        float lo = bf2f(w[q] << 16);           // element b = 2q
        float hi = bf2f(w[q] & 0xffff0000u);   // element b = 2q+1
        m = fmaf(lo, b[2 * q],     m);
        m = fmaf(hi, b[2 * q + 1], m);
    }

    atomicAdd(out + (size_t)dst * ADIM + lane, m);
}

extern "C" void kernel_launch(void* const* d_in, const int* in_sizes, int n_in,
                              void* d_out, int out_size, void* d_ws, size_t ws_size,
                              hipStream_t stream) {
    const float* atom = (const float*)d_in[0];   // [4480, 64]  f32
    const float* bond = (const float*)d_in[1];   // [65536, 16] f32
    const int*   pair = (const int*)  d_in[2];   // [65536, 2]  int32
    const float* kern = (const float*)d_in[3];   // [16, 4096]  f32
    const float* bias = (const float*)d_in[4];   // [4096]      f32

    float* out = (float*)d_out;                  // [4480, 64]  f32
    unsigned short* U = (unsigned short*)d_ws;   // [4480, 1088] bf16 = 9.75 MB

    dim3 g1(NSEG / 64, UPITCH / 64);             // 70 x 17 tiles; by==0 zeroes out[]
    proj_kernel<<<g1, 256, 0, stream>>>(atom, kern, bias, U, out);

    edge_kernel<<<NEDGE / 4, 256, 0, stream>>>(bond, pair, U, out);
}